// Round 1
// baseline (1885.341 us; speedup 1.0000x reference)
//
#include <hip/hip_runtime.h>

#define TPB 256
constexpr float EPSV = 1e-5f;

// ---------------- degree / normalization ----------------

__global__ void k_deginit(float* __restrict__ deg, int N) {
  int i = blockIdx.x * blockDim.x + threadIdx.x;
  if (i < N) deg[i] = 1.0f;  // self-loop weight
}

__global__ void k_degatomic(const int* __restrict__ col, const float* __restrict__ w,
                            float* __restrict__ deg, int E) {
  int e = blockIdx.x * blockDim.x + threadIdx.x;
  if (e < E) unsafeAtomicAdd(&deg[col[e]], w[e]);
}

__global__ void k_dinv(const float* __restrict__ deg, float* __restrict__ dinv, int N) {
  int i = blockIdx.x * blockDim.x + threadIdx.x;
  if (i < N) {
    float d = deg[i];
    dinv[i] = d > 0.0f ? rsqrtf(fmaxf(d, EPSV)) : 0.0f;
  }
}

__global__ void k_norm(const int* __restrict__ row, const int* __restrict__ col,
                       const float* __restrict__ w, const float* __restrict__ dinv,
                       float* __restrict__ nrm, int E) {
  int e = blockIdx.x * blockDim.x + threadIdx.x;
  if (e < E) nrm[e] = dinv[row[e]] * w[e] * dinv[col[e]];
}

// ---------------- per-layer transform: h(BN+relu of in) @ W, plus self-loop init ----------------
// 8 nodes per block, 32 lanes per node (lane = output channel). Reads `in` rows fully
// before overwriting `out` rows (safe even when in == out, rows are block-local).

template <int IN, bool BN>
__global__ void k_transform(const float* __restrict__ in, const float* __restrict__ W,
                            const float* __restrict__ ss, const float* __restrict__ dinv,
                            float* __restrict__ t, float* __restrict__ out, int N) {
  __shared__ float Ws[IN * 32];
  __shared__ float hs[8 * IN];
  const int tid = threadIdx.x;
  const int n0 = blockIdx.x * 8;
  for (int k = tid; k < IN * 32; k += TPB) Ws[k] = W[k];
  for (int k = tid; k < 8 * IN; k += TPB) {
    int node = n0 + k / IN;
    float v = 0.0f;
    if (node < N) {
      v = in[n0 * IN + k];
      if constexpr (BN) {
        int c = k % IN;  // IN == 32 when BN
        v = fmaxf(v * ss[c] + ss[32 + c], 0.0f);
      }
    }
    hs[k] = v;
  }
  __syncthreads();
  const int j = tid >> 5, c = tid & 31;
  const int node = n0 + j;
  if (node < N) {
    float acc = 0.0f;
#pragma unroll
    for (int k = 0; k < IN; ++k) acc += hs[j * IN + k] * Ws[k * 32 + c];
    float dv = dinv[node];
    t[node * 32 + c] = acc;
    out[node * 32 + c] = dv * dv * acc;  // self-loop contribution == init
  }
}

// ---------------- edge scatter: out[col] += norm * t[row] ----------------

__global__ void k_scatter(const int* __restrict__ row, const int* __restrict__ col,
                          const float* __restrict__ nrm, const float* __restrict__ t,
                          float* __restrict__ out, int E) {
  int idx = blockIdx.x * blockDim.x + threadIdx.x;
  if (idx >= E * 32) return;
  int e = idx >> 5, c = idx & 31;
  float v = nrm[e] * t[row[e] * 32 + c];
  unsafeAtomicAdd(&out[col[e] * 32 + c], v);
}

// ---------------- BN stats over node axis ----------------

__global__ void k_stats(const float* __restrict__ x, float* __restrict__ gstats, int total) {
  __shared__ float ls[TPB], lq[TPB];
  int tid = threadIdx.x;
  float s = 0.f, q = 0.f;
  // stride is a multiple of 32 -> each thread stays on one channel (tid & 31)
  for (int idx = blockIdx.x * TPB + tid; idx < total; idx += gridDim.x * TPB) {
    float v = x[idx];
    s += v;
    q += v * v;
  }
  ls[tid] = s; lq[tid] = q;
  __syncthreads();
  for (int off = TPB / 2; off >= 32; off >>= 1) {
    if (tid < off) { ls[tid] += ls[tid + off]; lq[tid] += lq[tid + off]; }
    __syncthreads();
  }
  if (tid < 32) {
    unsafeAtomicAdd(&gstats[tid], ls[tid]);
    unsafeAtomicAdd(&gstats[32 + tid], lq[tid]);
  }
}

__global__ void k_bnfin(const float* __restrict__ gstats, const float* __restrict__ gamma,
                        const float* __restrict__ beta, float* __restrict__ ss, float invN) {
  int c = threadIdx.x;
  if (c < 32) {
    float m = gstats[c] * invN;
    float v = gstats[32 + c] * invN - m * m;
    float sc = gamma[c] * rsqrtf(v + EPSV);
    ss[c] = sc;
    ss[32 + c] = beta[c] - m * sc;
  }
}

// ---------------- global add pool (batch is sorted) ----------------

__global__ void k_pool(const float* __restrict__ h, const int* __restrict__ batch,
                       const float* __restrict__ b3, float* __restrict__ pool, int N) {
  __shared__ float red[TPB];
  int g = blockIdx.x, tid = threadIdx.x;
  int lo = 0, hi = N;
  while (lo < hi) { int mid = (lo + hi) >> 1; if (batch[mid] < g) lo = mid + 1; else hi = mid; }
  int start = lo;
  hi = N;
  while (lo < hi) { int mid = (lo + hi) >> 1; if (batch[mid] < g + 1) lo = mid + 1; else hi = mid; }
  int end = lo;
  int j = tid >> 5, c = tid & 31;
  float acc = 0.f;
  for (int i = start + j; i < end; i += 8) acc += h[i * 32 + c];
  red[tid] = acc;
  __syncthreads();
  for (int off = 128; off >= 32; off >>= 1) {
    if (tid < off) red[tid] += red[tid + off];
    __syncthreads();
  }
  if (tid < 32) pool[g * 32 + tid] = red[tid] + (float)(end - start) * b3[tid];
}

// ---------------- final MLP: z = pool@Wm0+bm0, BN over 512 rows, relu, @Wm1+bm1 ----------------
// single block of 256 threads, 2 rows per thread, everything in registers/LDS.

__global__ void k_mlp(const float* __restrict__ pool, const float* __restrict__ Wm0,
                      const float* __restrict__ bm0, const float* __restrict__ bng,
                      const float* __restrict__ bnb, const float* __restrict__ Wm1,
                      const float* __restrict__ bm1, float* __restrict__ out) {
  __shared__ float Ws[32 * 32];
  __shared__ float lsum[32], lsq[32];
  __shared__ float sc[32], sh[32];
  int tid = threadIdx.x;
  for (int k = tid; k < 1024; k += TPB) Ws[k] = Wm0[k];
  if (tid < 32) { lsum[tid] = 0.f; lsq[tid] = 0.f; }
  __syncthreads();
  float z0[32], z1[32];
  const int r0 = tid, r1 = tid + 256;
  {
    float p[32];
#pragma unroll
    for (int k = 0; k < 32; ++k) p[k] = pool[r0 * 32 + k];
#pragma unroll
    for (int c = 0; c < 32; ++c) {
      float a = bm0[c];
#pragma unroll
      for (int k = 0; k < 32; ++k) a += p[k] * Ws[k * 32 + c];
      z0[c] = a;
    }
#pragma unroll
    for (int k = 0; k < 32; ++k) p[k] = pool[r1 * 32 + k];
#pragma unroll
    for (int c = 0; c < 32; ++c) {
      float a = bm0[c];
#pragma unroll
      for (int k = 0; k < 32; ++k) a += p[k] * Ws[k * 32 + c];
      z1[c] = a;
    }
  }
  for (int k = 0; k < 32; ++k) {
    int c = (k + tid) & 31;  // rotate to spread LDS atomic contention
    atomicAdd(&lsum[c], z0[c] + z1[c]);
    atomicAdd(&lsq[c], z0[c] * z0[c] + z1[c] * z1[c]);
  }
  __syncthreads();
  if (tid < 32) {
    float m = lsum[tid] / 512.0f;
    float v = lsq[tid] / 512.0f - m * m;
    float s = bng[tid] * rsqrtf(v + EPSV);
    sc[tid] = s;
    sh[tid] = bnb[tid] - m * s;
  }
  __syncthreads();
  float o0 = bm1[0], o1 = bm1[1];
#pragma unroll
  for (int c = 0; c < 32; ++c) {
    float hc = fmaxf(z0[c] * sc[c] + sh[c], 0.f);
    o0 += hc * Wm1[c * 2 + 0];
    o1 += hc * Wm1[c * 2 + 1];
  }
  out[r0 * 2 + 0] = o0; out[r0 * 2 + 1] = o1;
  o0 = bm1[0]; o1 = bm1[1];
#pragma unroll
  for (int c = 0; c < 32; ++c) {
    float hc = fmaxf(z1[c] * sc[c] + sh[c], 0.f);
    o0 += hc * Wm1[c * 2 + 0];
    o1 += hc * Wm1[c * 2 + 1];
  }
  out[r1 * 2 + 0] = o0; out[r1 * 2 + 1] = o1;
}

// ---------------- launch ----------------

extern "C" void kernel_launch(void* const* d_in, const int* in_sizes, int n_in,
                              void* d_out, int out_size, void* d_ws, size_t ws_size,
                              hipStream_t stream) {
  const float* x     = (const float*)d_in[0];
  const int*   ei    = (const int*)d_in[1];
  const float* ea    = (const float*)d_in[2];
  const int*   batch = (const int*)d_in[3];
  const float* W0    = (const float*)d_in[4];
  const float* W1    = (const float*)d_in[6];
  const float* W2    = (const float*)d_in[8];
  const float* W3    = (const float*)d_in[10];
  const float* b3    = (const float*)d_in[11];
  const float* bng   = (const float*)d_in[12];  // [3,32]
  const float* bnb   = (const float*)d_in[13];
  const float* Wm0   = (const float*)d_in[14];
  const float* bm0   = (const float*)d_in[15];
  const float* bnmg  = (const float*)d_in[16];
  const float* bnmb  = (const float*)d_in[17];
  const float* Wm1   = (const float*)d_in[18];
  const float* bm1   = (const float*)d_in[19];
  float* out = (float*)d_out;

  const int N = in_sizes[3];
  const int E = in_sizes[2];
  const int* row = ei;
  const int* col = ei + E;

  float* ws   = (float*)d_ws;
  float* deg  = ws; ws += N;
  float* dinv = ws; ws += N;
  float* nrm  = ws; ws += E;
  float* B0   = ws; ws += (size_t)N * 32;  // t
  float* B1   = ws; ws += (size_t)N * 32;  // out (aggregated)
  float* stats = ws; ws += 3 * 64;
  float* ss    = ws; ws += 3 * 64;
  float* pool  = ws; ws += 512 * 32;

  hipMemsetAsync(stats, 0, 3 * 64 * sizeof(float), stream);

  const int nb_n = (N + TPB - 1) / TPB;
  const int nb_e = (E + TPB - 1) / TPB;
  const int nb_t = (N + 7) / 8;
  const long long totS = (long long)E * 32;
  const int nb_s = (int)((totS + TPB - 1) / TPB);
  const int total32 = N * 32;
  const float invN = 1.0f / (float)N;

  k_deginit<<<nb_n, TPB, 0, stream>>>(deg, N);
  k_degatomic<<<nb_e, TPB, 0, stream>>>(col, ea, deg, E);
  k_dinv<<<nb_n, TPB, 0, stream>>>(deg, dinv, N);
  k_norm<<<nb_e, TPB, 0, stream>>>(row, col, ea, dinv, nrm, E);

  // layer 0 (x[N,7] @ W0)
  k_transform<7, false><<<nb_t, TPB, 0, stream>>>(x, W0, nullptr, dinv, B0, B1, N);
  k_scatter<<<nb_s, TPB, 0, stream>>>(row, col, nrm, B0, B1, E);
  k_stats<<<1024, TPB, 0, stream>>>(B1, stats, total32);
  k_bnfin<<<1, 32, 0, stream>>>(stats, bng, bnb, ss, invN);

  // layer 1
  k_transform<32, true><<<nb_t, TPB, 0, stream>>>(B1, W1, ss, dinv, B0, B1, N);
  k_scatter<<<nb_s, TPB, 0, stream>>>(row, col, nrm, B0, B1, E);
  k_stats<<<1024, TPB, 0, stream>>>(B1, stats + 64, total32);
  k_bnfin<<<1, 32, 0, stream>>>(stats + 64, bng + 32, bnb + 32, ss + 64, invN);

  // layer 2
  k_transform<32, true><<<nb_t, TPB, 0, stream>>>(B1, W2, ss + 64, dinv, B0, B1, N);
  k_scatter<<<nb_s, TPB, 0, stream>>>(row, col, nrm, B0, B1, E);
  k_stats<<<1024, TPB, 0, stream>>>(B1, stats + 128, total32);
  k_bnfin<<<1, 32, 0, stream>>>(stats + 128, bng + 64, bnb + 64, ss + 128, invN);

  // layer 3 (no BN on output)
  k_transform<32, true><<<nb_t, TPB, 0, stream>>>(B1, W3, ss + 128, dinv, B0, B1, N);
  k_scatter<<<nb_s, TPB, 0, stream>>>(row, col, nrm, B0, B1, E);

  // pool + MLP head
  k_pool<<<512, TPB, 0, stream>>>(B1, batch, b3, pool, N);
  k_mlp<<<1, TPB, 0, stream>>>(pool, Wm0, bm0, bnmg, bnmb, Wm1, bm1, out);
}

// Round 2
// 1476.165 us; speedup vs baseline: 1.2772x; 1.2772x over previous
//
#include <hip/hip_runtime.h>

#define TPB 256
constexpr float EPSV = 1e-5f;

// =================== CSR build (counting sort of edges by col) ===================

__global__ void k_hist(const int* __restrict__ col, int* __restrict__ cnt, int E) {
  int e = blockIdx.x * blockDim.x + threadIdx.x;
  if (e < E) atomicAdd(&cnt[col[e]], 1);
}

#define SCAN_T 512
#define SCAN_E 8
#define SCAN_BLK (SCAN_T * SCAN_E)  // 4096

__global__ void k_scan_partial(const int* __restrict__ cnt, int* __restrict__ bsum, int N) {
  __shared__ int red[SCAN_T];
  int tid = threadIdx.x;
  int base = blockIdx.x * SCAN_BLK + tid * SCAN_E;
  int s = 0;
#pragma unroll
  for (int k = 0; k < SCAN_E; ++k) {
    int i = base + k;
    if (i < N) s += cnt[i];
  }
  red[tid] = s;
  __syncthreads();
  for (int off = SCAN_T / 2; off > 0; off >>= 1) {
    if (tid < off) red[tid] += red[tid + off];
    __syncthreads();
  }
  if (tid == 0) bsum[blockIdx.x] = red[0];
}

__global__ void k_scan_bsum(int* __restrict__ bsum, int* __restrict__ ptrN, int nb, int E) {
  if (threadIdx.x == 0) {
    int run = 0;
    for (int b = 0; b < nb; ++b) { int v = bsum[b]; bsum[b] = run; run += v; }
    *ptrN = E;  // ptr[N]
  }
}

__global__ void k_scan_final(const int* __restrict__ cnt, const int* __restrict__ bsum,
                             int* __restrict__ ptr, int* __restrict__ cur, int N) {
  __shared__ int red[SCAN_T];
  int tid = threadIdx.x;
  int base = blockIdx.x * SCAN_BLK + tid * SCAN_E;
  int loc[SCAN_E];
  int s = 0;
#pragma unroll
  for (int k = 0; k < SCAN_E; ++k) {
    int i = base + k;
    int v = (i < N) ? cnt[i] : 0;
    loc[k] = s;
    s += v;
  }
  red[tid] = s;
  __syncthreads();
  for (int off = 1; off < SCAN_T; off <<= 1) {
    int v = (tid >= off) ? red[tid - off] : 0;
    __syncthreads();
    red[tid] += v;
    __syncthreads();
  }
  int tbase = bsum[blockIdx.x] + (tid > 0 ? red[tid - 1] : 0);
#pragma unroll
  for (int k = 0; k < SCAN_E; ++k) {
    int i = base + k;
    if (i < N) { int v = tbase + loc[k]; ptr[i] = v; cur[i] = v; }
  }
}

__global__ void k_fill(const int* __restrict__ row, const int* __restrict__ col,
                       const float* __restrict__ w, int* __restrict__ cur,
                       uint2* __restrict__ pk, int E) {
  int e = blockIdx.x * blockDim.x + threadIdx.x;
  if (e < E) {
    int pos = atomicAdd(&cur[col[e]], 1);
    pk[pos] = make_uint2((unsigned)row[e], __float_as_uint(w[e]));
  }
}

// deg[i] = 1 (self-loop) + sum of incoming weights; dinv = rsqrt
__global__ void k_degdinv(const uint2* __restrict__ pk, const int* __restrict__ ptr,
                          float* __restrict__ dinv, int N) {
  int i = blockIdx.x * blockDim.x + threadIdx.x;
  if (i >= N) return;
  int p0 = ptr[i], p1 = ptr[i + 1];
  float d = 1.0f;
  for (int p = p0; p < p1; ++p) d += __uint_as_float(pk[p].y);
  dinv[i] = d > 0.0f ? rsqrtf(fmaxf(d, EPSV)) : 0.0f;
}

// overwrite packed weight with norm = dinv[row]*w*dinv[col]
__global__ void k_nrmcsr(uint2* __restrict__ pk, const int* __restrict__ ptr,
                         const float* __restrict__ dinv, int N) {
  int i = blockIdx.x * blockDim.x + threadIdx.x;
  if (i >= N) return;
  int p0 = ptr[i], p1 = ptr[i + 1];
  float dvc = dinv[i];
  for (int p = p0; p < p1; ++p) {
    uint2 e = pk[p];
    pk[p].y = __float_as_uint(dinv[e.x] * __uint_as_float(e.y) * dvc);
  }
}

// =================== per-layer transform: t = relu(BN(in)) @ W ===================
// 8 nodes per block, 32 lanes per node (lane = output channel).

template <int IN, bool BN>
__global__ void k_transform(const float* __restrict__ in, const float* __restrict__ W,
                            const float* __restrict__ ss, float* __restrict__ t, int N) {
  __shared__ float Ws[IN * 32];
  __shared__ float hs[8 * IN];
  const int tid = threadIdx.x;
  const int n0 = blockIdx.x * 8;
  for (int k = tid; k < IN * 32; k += TPB) Ws[k] = W[k];
  for (int k = tid; k < 8 * IN; k += TPB) {
    int node = n0 + k / IN;
    float v = 0.0f;
    if (node < N) {
      v = in[n0 * IN + k];
      if constexpr (BN) {
        int c = k % IN;  // IN == 32 when BN
        v = fmaxf(v * ss[c] + ss[32 + c], 0.0f);
      }
    }
    hs[k] = v;
  }
  __syncthreads();
  const int j = tid >> 5, c = tid & 31;
  const int node = n0 + j;
  if (node < N) {
    float acc = 0.0f;
#pragma unroll
    for (int k = 0; k < IN; ++k) acc += hs[j * IN + k] * Ws[k * 32 + c];
    t[(size_t)node * 32 + c] = acc;
  }
}

// =================== CSR gather: out[n] = dinv[n]^2*t[n] + sum nrm*t[row] ===================

__global__ void k_gather(const uint2* __restrict__ pk, const int* __restrict__ ptr,
                         const float* __restrict__ dinv, const float* __restrict__ t,
                         float* __restrict__ out, int N) {
  const int tid = threadIdx.x;
  const int j = tid >> 5, c = tid & 31;
  const int n = blockIdx.x * 8 + j;
  if (n >= N) return;
  const int p0 = ptr[n], p1 = ptr[n + 1];
  const float dvn = dinv[n];
  float acc = dvn * dvn * t[(size_t)n * 32 + c];
  int p = p0;
  // unroll by 2 to keep more loads in flight
  for (; p + 1 < p1; p += 2) {
    uint2 e0 = pk[p], e1 = pk[p + 1];
    float v0 = t[(size_t)e0.x * 32 + c];
    float v1 = t[(size_t)e1.x * 32 + c];
    acc += __uint_as_float(e0.y) * v0;
    acc += __uint_as_float(e1.y) * v1;
  }
  if (p < p1) {
    uint2 e0 = pk[p];
    acc += __uint_as_float(e0.y) * t[(size_t)e0.x * 32 + c];
  }
  out[(size_t)n * 32 + c] = acc;
}

// =================== BN stats over node axis ===================

__global__ void k_stats(const float* __restrict__ x, float* __restrict__ gstats, int total) {
  __shared__ float ls[TPB], lq[TPB];
  int tid = threadIdx.x;
  float s = 0.f, q = 0.f;
  for (int idx = blockIdx.x * TPB + tid; idx < total; idx += gridDim.x * TPB) {
    float v = x[idx];
    s += v;
    q += v * v;
  }
  ls[tid] = s; lq[tid] = q;
  __syncthreads();
  for (int off = TPB / 2; off >= 32; off >>= 1) {
    if (tid < off) { ls[tid] += ls[tid + off]; lq[tid] += lq[tid + off]; }
    __syncthreads();
  }
  if (tid < 32) {
    unsafeAtomicAdd(&gstats[tid], ls[tid]);
    unsafeAtomicAdd(&gstats[32 + tid], lq[tid]);
  }
}

__global__ void k_bnfin(const float* __restrict__ gstats, const float* __restrict__ gamma,
                        const float* __restrict__ beta, float* __restrict__ ss, float invN) {
  int c = threadIdx.x;
  if (c < 32) {
    float m = gstats[c] * invN;
    float v = gstats[32 + c] * invN - m * m;
    float sc = gamma[c] * rsqrtf(v + EPSV);
    ss[c] = sc;
    ss[32 + c] = beta[c] - m * sc;
  }
}

// =================== global add pool (batch is sorted) ===================

__global__ void k_pool(const float* __restrict__ h, const int* __restrict__ batch,
                       const float* __restrict__ b3, float* __restrict__ pool, int N) {
  __shared__ float red[TPB];
  int g = blockIdx.x, tid = threadIdx.x;
  int lo = 0, hi = N;
  while (lo < hi) { int mid = (lo + hi) >> 1; if (batch[mid] < g) lo = mid + 1; else hi = mid; }
  int start = lo;
  hi = N;
  while (lo < hi) { int mid = (lo + hi) >> 1; if (batch[mid] < g + 1) lo = mid + 1; else hi = mid; }
  int end = lo;
  int j = tid >> 5, c = tid & 31;
  float acc = 0.f;
  for (int i = start + j; i < end; i += 8) acc += h[(size_t)i * 32 + c];
  red[tid] = acc;
  __syncthreads();
  for (int off = 128; off >= 32; off >>= 1) {
    if (tid < off) red[tid] += red[tid + off];
    __syncthreads();
  }
  if (tid < 32) pool[g * 32 + tid] = red[tid] + (float)(end - start) * b3[tid];
}

// =================== final MLP ===================

__global__ void k_mlp(const float* __restrict__ pool, const float* __restrict__ Wm0,
                      const float* __restrict__ bm0, const float* __restrict__ bng,
                      const float* __restrict__ bnb, const float* __restrict__ Wm1,
                      const float* __restrict__ bm1, float* __restrict__ out) {
  __shared__ float Ws[32 * 32];
  __shared__ float lsum[32], lsq[32];
  __shared__ float sc[32], sh[32];
  int tid = threadIdx.x;
  for (int k = tid; k < 1024; k += TPB) Ws[k] = Wm0[k];
  if (tid < 32) { lsum[tid] = 0.f; lsq[tid] = 0.f; }
  __syncthreads();
  float z0[32], z1[32];
  const int r0 = tid, r1 = tid + 256;
  {
    float p[32];
#pragma unroll
    for (int k = 0; k < 32; ++k) p[k] = pool[r0 * 32 + k];
#pragma unroll
    for (int c = 0; c < 32; ++c) {
      float a = bm0[c];
#pragma unroll
      for (int k = 0; k < 32; ++k) a += p[k] * Ws[k * 32 + c];
      z0[c] = a;
    }
#pragma unroll
    for (int k = 0; k < 32; ++k) p[k] = pool[r1 * 32 + k];
#pragma unroll
    for (int c = 0; c < 32; ++c) {
      float a = bm0[c];
#pragma unroll
      for (int k = 0; k < 32; ++k) a += p[k] * Ws[k * 32 + c];
      z1[c] = a;
    }
  }
  for (int k = 0; k < 32; ++k) {
    int c = (k + tid) & 31;
    atomicAdd(&lsum[c], z0[c] + z1[c]);
    atomicAdd(&lsq[c], z0[c] * z0[c] + z1[c] * z1[c]);
  }
  __syncthreads();
  if (tid < 32) {
    float m = lsum[tid] / 512.0f;
    float v = lsq[tid] / 512.0f - m * m;
    float s = bng[tid] * rsqrtf(v + EPSV);
    sc[tid] = s;
    sh[tid] = bnb[tid] - m * s;
  }
  __syncthreads();
  float o0 = bm1[0], o1 = bm1[1];
#pragma unroll
  for (int c = 0; c < 32; ++c) {
    float hc = fmaxf(z0[c] * sc[c] + sh[c], 0.f);
    o0 += hc * Wm1[c * 2 + 0];
    o1 += hc * Wm1[c * 2 + 1];
  }
  out[r0 * 2 + 0] = o0; out[r0 * 2 + 1] = o1;
  o0 = bm1[0]; o1 = bm1[1];
#pragma unroll
  for (int c = 0; c < 32; ++c) {
    float hc = fmaxf(z1[c] * sc[c] + sh[c], 0.f);
    o0 += hc * Wm1[c * 2 + 0];
    o1 += hc * Wm1[c * 2 + 1];
  }
  out[r1 * 2 + 0] = o0; out[r1 * 2 + 1] = o1;
}

// =================== launch ===================

extern "C" void kernel_launch(void* const* d_in, const int* in_sizes, int n_in,
                              void* d_out, int out_size, void* d_ws, size_t ws_size,
                              hipStream_t stream) {
  const float* x     = (const float*)d_in[0];
  const int*   ei    = (const int*)d_in[1];
  const float* ea    = (const float*)d_in[2];
  const int*   batch = (const int*)d_in[3];
  const float* W0    = (const float*)d_in[4];
  const float* W1    = (const float*)d_in[6];
  const float* W2    = (const float*)d_in[8];
  const float* W3    = (const float*)d_in[10];
  const float* b3    = (const float*)d_in[11];
  const float* bng   = (const float*)d_in[12];  // [3,32]
  const float* bnb   = (const float*)d_in[13];
  const float* Wm0   = (const float*)d_in[14];
  const float* bm0   = (const float*)d_in[15];
  const float* bnmg  = (const float*)d_in[16];
  const float* bnmb  = (const float*)d_in[17];
  const float* Wm1   = (const float*)d_in[18];
  const float* bm1   = (const float*)d_in[19];
  float* out = (float*)d_out;

  const int N = in_sizes[3];
  const int E = in_sizes[2];
  const int* row = ei;
  const int* col = ei + E;

  char* wsb = (char*)d_ws;
  auto alloc = [&](size_t bytes) { char* p = wsb; wsb += (bytes + 255) & ~size_t(255); return p; };
  int*   cnt  = (int*)alloc((size_t)(N + 1) * 4);   // also reused as nothing after scan
  int*   ptr  = (int*)alloc((size_t)(N + 1) * 4);
  int*   cur  = (int*)alloc((size_t)N * 4);
  int*   bsum = (int*)alloc(1024 * 4);
  uint2* pk   = (uint2*)alloc((size_t)E * 8);
  float* dinv = (float*)alloc((size_t)N * 4);
  float* B0   = (float*)alloc((size_t)N * 32 * 4);
  float* B1   = (float*)alloc((size_t)N * 32 * 4);
  float* stats = (float*)alloc(3 * 64 * 4);
  float* ss    = (float*)alloc(3 * 64 * 4);
  float* pool  = (float*)alloc(512 * 32 * 4);

  hipMemsetAsync(cnt, 0, (size_t)N * 4, stream);
  hipMemsetAsync(stats, 0, 3 * 64 * 4, stream);

  const int nb_n = (N + TPB - 1) / TPB;
  const int nb_e = (E + TPB - 1) / TPB;
  const int nb_t = (N + 7) / 8;
  const int nb_scan = (N + SCAN_BLK - 1) / SCAN_BLK;
  const int total32 = N * 32;
  const float invN = 1.0f / (float)N;

  // ---- CSR build ----
  k_hist<<<nb_e, TPB, 0, stream>>>(col, cnt, E);
  k_scan_partial<<<nb_scan, SCAN_T, 0, stream>>>(cnt, bsum, N);
  k_scan_bsum<<<1, 1, 0, stream>>>(bsum, ptr + N, nb_scan, E);
  k_scan_final<<<nb_scan, SCAN_T, 0, stream>>>(cnt, bsum, ptr, cur, N);
  k_fill<<<nb_e, TPB, 0, stream>>>(row, col, ea, cur, pk, E);
  k_degdinv<<<nb_n, TPB, 0, stream>>>(pk, ptr, dinv, N);
  k_nrmcsr<<<nb_n, TPB, 0, stream>>>(pk, ptr, dinv, N);

  // ---- layer 0 (x[N,7] @ W0) ----
  k_transform<7, false><<<nb_t, TPB, 0, stream>>>(x, W0, nullptr, B0, N);
  k_gather<<<nb_t, TPB, 0, stream>>>(pk, ptr, dinv, B0, B1, N);
  k_stats<<<1024, TPB, 0, stream>>>(B1, stats, total32);
  k_bnfin<<<1, 32, 0, stream>>>(stats, bng, bnb, ss, invN);

  // ---- layer 1 ----
  k_transform<32, true><<<nb_t, TPB, 0, stream>>>(B1, W1, ss, B0, N);
  k_gather<<<nb_t, TPB, 0, stream>>>(pk, ptr, dinv, B0, B1, N);
  k_stats<<<1024, TPB, 0, stream>>>(B1, stats + 64, total32);
  k_bnfin<<<1, 32, 0, stream>>>(stats + 64, bng + 32, bnb + 32, ss + 64, invN);

  // ---- layer 2 ----
  k_transform<32, true><<<nb_t, TPB, 0, stream>>>(B1, W2, ss + 64, B0, N);
  k_gather<<<nb_t, TPB, 0, stream>>>(pk, ptr, dinv, B0, B1, N);
  k_stats<<<1024, TPB, 0, stream>>>(B1, stats + 128, total32);
  k_bnfin<<<1, 32, 0, stream>>>(stats + 128, bng + 64, bnb + 64, ss + 128, invN);

  // ---- layer 3 (no BN on output) ----
  k_transform<32, true><<<nb_t, TPB, 0, stream>>>(B1, W3, ss + 128, B0, N);
  k_gather<<<nb_t, TPB, 0, stream>>>(pk, ptr, dinv, B0, B1, N);

  // ---- pool + MLP head ----
  k_pool<<<512, TPB, 0, stream>>>(B1, batch, b3, pool, N);
  k_mlp<<<1, TPB, 0, stream>>>(pool, Wm0, bm0, bnmg, bnmb, Wm1, bm1, out);
}